// Round 3
// baseline (47.071 us; speedup 1.0000x reference)
//
#include <hip/hip_runtime.h>
#include <stdint.h>

#define AS_G __attribute__((address_space(1)))
#define AS_L __attribute__((address_space(3)))

typedef __bf16 bf16x8 __attribute__((ext_vector_type(8)));
typedef float  f32x4  __attribute__((ext_vector_type(4)));

static constexpr int NIMG = 16, CIN = 128, H = 64, W = 64, OCH = 128;
static constexpr int HO = 62, WO = 62;
static constexpr int PIX = HO * WO;            // 3844
static constexpr int K_TOT = CIN * 9;          // 1152
static constexpr int KSTEPS = 36;              // BK = 32
static constexpr int NBLK = NIMG * 31;         // 496 blocks, one (n, row-pair) each
// LDS layout: B double buffer [2][8192B] at 0, A-resident [4][64][128]bf16 at 16384
static constexpr int LDS_BYTES = 81920;

__device__ __forceinline__ unsigned short f2bf(float f) {
    union { float f; uint32_t u; } v; v.f = f;
    uint32_t u = v.u;
    return (unsigned short)((u + 0x7FFFu + ((u >> 16) & 1u)) >> 16);
}

// Fused prep: blocks [0,1024): NCHW fp32 -> NHWC bf16; blocks [1024,1600): weight prep.
__global__ __launch_bounds__(256) void prep_kernel(const float* __restrict__ x,
                                                   const float* __restrict__ wsrc,
                                                   unsigned short* __restrict__ xt,
                                                   unsigned short* __restrict__ bpd) {
    __shared__ float lds[CIN][W + 4];
    if (blockIdx.x < NIMG * H) {
        const int n   = blockIdx.x >> 6;
        const int h   = blockIdx.x & 63;
        const int tid = threadIdx.x;
        {
            const int c  = tid >> 1;
            const int w0 = (tid & 1) * 32;
            const float* src = x + (((size_t)(n * CIN + c) * H + h) * W + w0);
            #pragma unroll
            for (int j = 0; j < 8; ++j) {
                float4 v = *reinterpret_cast<const float4*>(src + j * 4);
                *reinterpret_cast<float4*>(&lds[c][w0 + j * 4]) = v;
            }
        }
        __syncthreads();
        {
            const int w  = tid >> 2;
            const int c0 = (tid & 3) * 32;
            unsigned short* dst = xt + (((size_t)(n * H + h) * W + w) * CIN + c0);
            uint32_t pk[16];
            #pragma unroll
            for (int j = 0; j < 16; ++j) {
                uint32_t lo = f2bf(lds[c0 + 2 * j][w]);
                uint32_t hi = f2bf(lds[c0 + 2 * j + 1][w]);
                pk[j] = lo | (hi << 16);
            }
            #pragma unroll
            for (int j = 0; j < 4; ++j) {
                *reinterpret_cast<uint4*>(dst + j * 8) =
                    make_uint4(pk[4 * j], pk[4 * j + 1], pk[4 * j + 2], pk[4 * j + 3]);
            }
        }
    } else {
        int tid = (blockIdx.x - NIMG * H) * 256 + threadIdx.x;
        if (tid < OCH * K_TOT) {
            int o  = tid / K_TOT;
            int kp = tid - o * K_TOT;   // kp = t*128 + c
            int t  = kp >> 7;
            int c  = kp & 127;
            bpd[tid] = f2bf(wsrc[o * K_TOT + c * 9 + t]);
        }
    }
}

// Implicit-GEMM conv, A-resident-in-LDS version.
// Block = one (n, output-row-pair). M-tile 128 (124 valid), N = 128 o, BK = 32.
// mfma(bfr, af, acc): D rows = o, D cols = m (coalesced stores).
__global__ __launch_bounds__(256) void gemm_kernel(const unsigned short* __restrict__ xt,
                                                   const unsigned short* __restrict__ bp,
                                                   const float* __restrict__ bias,
                                                   float* __restrict__ out) {
    extern __shared__ char lds[];
    const int tid  = threadIdx.x;
    const int wv   = tid >> 6;
    const int lane = tid & 63;
    const int lr   = lane & 15, lq = lane >> 4, lq16 = lq * 16;
    const int wo   = wv >> 1;      // o-half of this wave
    const int wm   = wv & 1;       // which of the 2 output rows
    const int bid  = blockIdx.x;
    const int n    = bid / 31;
    const int y2   = bid - n * 31;             // row-pair: out rows 2*y2, 2*y2+1

    // ---- stage A: 4 input rows [ri][w][c], 64 KB, swizzle byte^=((w&7)<<4) ----
    const unsigned short* xrow = xt + (size_t)(n * H + y2 * 2) * W * CIN;
    #pragma unroll
    for (int p = 0; p < 16; ++p) {
        int slot = (wv * 16 + p) * 64 + lane;          // 16B slots, 4096 total
        int ri = slot >> 10;                           // 1024 slots per input row
        int w  = (slot >> 4) & 63;                     // 16 slots per w (256B)
        int q  = slot & 15;
        int srco = (ri * W + w) * CIN + ((q * 8) ^ ((w & 7) << 3));   // elems
        __builtin_amdgcn_global_load_lds(
            (AS_G unsigned int*)(xrow + srco),
            (AS_L unsigned int*)(lds + 16384 + (wv * 16 + p) * 1024), 16, 0, 0);
    }
    // ---- B staging setup: buffer 8192B = 512 slots; row = o>>1 (128B),
    // phys slot-in-half = lq_log ^ ((o>>1)&3) ----
    const unsigned short* bs0;
    const unsigned short* bs1;
    {
        int s2 = (wv * 2 + 0) * 64 + lane;
        int row = s2 >> 3, o = row * 2 + ((s2 >> 2) & 1), lql = (s2 & 3) ^ (row & 3);
        bs0 = bp + o * K_TOT + lql * 8;
        s2 = (wv * 2 + 1) * 64 + lane;
        row = s2 >> 3; o = row * 2 + ((s2 >> 2) & 1); lql = (s2 & 3) ^ (row & 3);
        bs1 = bp + o * K_TOT + lql * 8;
    }
    // prologue: stage B step 0 into buf 0
    __builtin_amdgcn_global_load_lds((AS_G unsigned int*)bs0,
        (AS_L unsigned int*)(lds + (wv * 2 + 0) * 1024), 16, 0, 0);
    __builtin_amdgcn_global_load_lds((AS_G unsigned int*)bs1,
        (AS_L unsigned int*)(lds + (wv * 2 + 1) * 1024), 16, 0, 0);
    bs0 += 32; bs1 += 32;
    __syncthreads();

    // ---- fragment read offsets ----
    int bfrOff[4];
    #pragma unroll
    for (int ni = 0; ni < 4; ++ni) {
        int o = wo * 64 + ni * 16 + lr;
        bfrOff[ni] = (o >> 1) * 128 + (o & 1) * 64 + (lq16 ^ (((o >> 1) & 3) << 4));
    }

    f32x4 acc[4][4];
    #pragma unroll
    for (int a = 0; a < 4; ++a)
        #pragma unroll
        for (int b = 0; b < 4; ++b)
            acc[a][b] = (f32x4){0.f, 0.f, 0.f, 0.f};

    unsigned bWr = 8192, bRd = 0;
    #pragma unroll 2
    for (int step = 0; step < KSTEPS; ++step) {
        if (step != KSTEPS - 1) {      // prefetch next B chunk into other buffer
            __builtin_amdgcn_global_load_lds((AS_G unsigned int*)bs0,
                (AS_L unsigned int*)(lds + bWr + (wv * 2 + 0) * 1024), 16, 0, 0);
            __builtin_amdgcn_global_load_lds((AS_G unsigned int*)bs1,
                (AS_L unsigned int*)(lds + bWr + (wv * 2 + 1) * 1024), 16, 0, 0);
            bs0 += 32; bs1 += 32;
        }
        const int t   = step >> 2;           // tap 0..8
        const int kh  = t / 3, kw = t - kh * 3;
        const int cb  = (step & 3) * 64 + lq16;          // logical col-byte in A row
        const int riO = 16384 + (kh + wm) * 16384;       // A plane for this out-row
        bf16x8 af[4], bfr[4];
        #pragma unroll
        for (int mi = 0; mi < 4; ++mi) {
            int w = mi * 16 + lr + kw;
            w = (w > 63) ? 63 : w;           // pad lanes (xloc>=62) read junk, masked later
            af[mi] = *(const bf16x8*)(lds + riO + w * 256 + (cb ^ ((w & 7) << 4)));
        }
        #pragma unroll
        for (int ni = 0; ni < 4; ++ni)
            bfr[ni] = *(const bf16x8*)(lds + bRd + bfrOff[ni]);
        #pragma unroll
        for (int mi = 0; mi < 4; ++mi)
            #pragma unroll
            for (int ni = 0; ni < 4; ++ni)
                acc[mi][ni] = __builtin_amdgcn_mfma_f32_16x16x32_bf16(
                    bfr[ni], af[mi], acc[mi][ni], 0, 0, 0);
        __syncthreads();
        bWr ^= 8192; bRd ^= 8192;
    }

    // ---- epilogue: D col = lane&15 = m (consecutive x), row = lq*4+j = o ----
    const int yrow = y2 * 2 + wm;
    float* ob = out + (size_t)n * OCH * PIX + yrow * WO;
    f32x4 bv[4];
    #pragma unroll
    for (int ni = 0; ni < 4; ++ni)
        bv[ni] = *(const f32x4*)(bias + wo * 64 + ni * 16 + lq * 4);
    #pragma unroll
    for (int mi = 0; mi < 4; ++mi) {
        int xl = mi * 16 + lr;
        if (xl < WO) {
            #pragma unroll
            for (int ni = 0; ni < 4; ++ni) {
                float* p = ob + (size_t)(wo * 64 + ni * 16 + lq * 4) * PIX + xl;
                #pragma unroll
                for (int j = 0; j < 4; ++j)
                    p[(size_t)j * PIX] = acc[mi][ni][j] + bv[ni][j];
            }
        }
    }
}

extern "C" void kernel_launch(void* const* d_in, const int* in_sizes, int n_in,
                              void* d_out, int out_size, void* d_ws, size_t ws_size,
                              hipStream_t stream) {
    const float* x    = (const float*)d_in[0];
    const float* wsrc = (const float*)d_in[1];
    const float* bias = (const float*)d_in[2];
    float* out = (float*)d_out;
    unsigned short* xt = (unsigned short*)d_ws;                 // 16 MiB NHWC bf16
    unsigned short* bp = xt + (size_t)NIMG * H * W * CIN;       // 288 KiB weights
    prep_kernel<<<dim3(NIMG * H + (OCH * K_TOT + 255) / 256), dim3(256), 0, stream>>>(
        x, wsrc, xt, bp);
    gemm_kernel<<<dim3(NBLK), dim3(256), LDS_BYTES, stream>>>(xt, bp, bias, out);
}